// Round 1
// baseline (37.251 us; speedup 1.0000x reference)
//
#include <hip/hip_runtime.h>

#define B_ 2
#define L_ 2048
#define H_ 8
#define HD 64
#define K_ 63
#define TQ 64
#define ROWS 126            // TQ + K - 1
#define SCALE 0.125f        // hd^-0.5

// One block = one (b, h, 64-query tile). 8 waves; each wave handles 4 pairs of
// consecutive queries. LDS holds the union key window (126 rows x 64 floats),
// XOR-swizzled at float4 granularity for conflict-free column reads.
__global__ __launch_bounds__(512, 2) void natten1d_kernel(
    const float* __restrict__ x, float* __restrict__ out)
{
    __shared__ float tile[ROWS * HD];

    const int tiles_per_bh = L_ / TQ;          // 32
    const int bid = blockIdx.x;
    const int bh  = bid / tiles_per_bh;
    const int t   = bid % tiles_per_bh;
    const int b   = bh / H_;
    const int h   = bh % H_;
    const int l0  = t * TQ;
    const int key_base = max(l0 - K_ / 2, 0);  // <= L-K for all our tiles

    const int tid = threadIdx.x;

    // ---- stage window into LDS (float4, swizzled) ----
    float4* t4w = (float4*)tile;
    for (int id = tid; id < ROWS * 16; id += 512) {
        const int r  = id >> 4;
        const int d4 = id & 15;
        const int gr = key_base + r;
        float4 v = make_float4(0.f, 0.f, 0.f, 0.f);
        if (gr < L_) {
            const float4* src =
                (const float4*)(x + (((size_t)b * L_ + gr) * H_ + h) * HD);
            v = src[d4];
        }
        t4w[r * 16 + (d4 ^ (r & 15))] = v;
    }
    __syncthreads();

    const int wave = tid >> 6;
    const int lane = tid & 63;
    const float4* t4 = (const float4*)tile;

    #pragma unroll
    for (int i = 0; i < TQ / 2 / 8; ++i) {      // 4 pair-iterations per wave
        const int pi = wave + 8 * i;
        const int l  = l0 + 2 * pi;

        const int s0 = min(max(l - K_ / 2, 0), L_ - K_);
        const int s1 = min(max(l + 1 - K_ / 2, 0), L_ - K_);
        const int off0 = s0 - key_base;
        const int d1   = s1 - s0;               // 0 or 1
        const int qr0  = l - key_base;
        const int qr1  = qr0 + 1;

        // ---- scores: lane j owns key row s0+j ----
        const int myrow = off0 + lane;
        const int rs    = myrow & 15;
        float a0 = 0.f, a1 = 0.f;
        #pragma unroll
        for (int d4 = 0; d4 < 16; ++d4) {
            const float4 kv = t4[myrow * 16 + (d4 ^ rs)];
            const float4 q0 = t4[qr0 * 16 + (d4 ^ (qr0 & 15))];   // broadcast
            const float4 q1 = t4[qr1 * 16 + (d4 ^ (qr1 & 15))];   // broadcast
            a0 += q0.x * kv.x + q0.y * kv.y + q0.z * kv.z + q0.w * kv.w;
            a1 += q1.x * kv.x + q1.y * kv.y + q1.z * kv.z + q1.w * kv.w;
        }

        const bool v0 = (lane <= K_ - 1);
        const bool v1 = (lane >= d1) && (lane <= d1 + K_ - 1);
        float s0v = v0 ? a0 * SCALE : -1e30f;
        float s1v = v1 ? a1 * SCALE : -1e30f;

        // ---- softmax across 64 lanes (butterfly) ----
        float m0 = s0v, m1 = s1v;
        #pragma unroll
        for (int o = 32; o; o >>= 1) {
            m0 = fmaxf(m0, __shfl_xor(m0, o));
            m1 = fmaxf(m1, __shfl_xor(m1, o));
        }
        const float e0 = __expf(s0v - m0);      // invalid lanes -> 0
        const float e1 = __expf(s1v - m1);
        float z0 = e0, z1 = e1;
        #pragma unroll
        for (int o = 32; o; o >>= 1) {
            z0 += __shfl_xor(z0, o);
            z1 += __shfl_xor(z1, o);
        }
        const float p0 = e0 * (1.0f / z0);
        const float p1 = e1 * (1.0f / z1);

        // ---- PV: lane d accumulates out[d]; p redistributed via readlane ----
        float o0 = 0.f, o1 = 0.f;
        const int d4l = lane >> 2, el = lane & 3;
        #pragma unroll 4
        for (int j = 0; j < 64; ++j) {
            const int r = off0 + j;
            const float kvv =
                tile[r * HD + (((d4l ^ (r & 15)) << 2) | el)];
            const float pj0 =
                __int_as_float(__builtin_amdgcn_readlane(__float_as_int(p0), j));
            const float pj1 =
                __int_as_float(__builtin_amdgcn_readlane(__float_as_int(p1), j));
            o0 = fmaf(pj0, kvv, o0);
            o1 = fmaf(pj1, kvv, o1);
        }

        float* dst0 = out + (((size_t)b * L_ + l) * H_ + h) * HD;
        dst0[lane]       = o0;
        dst0[H_ * HD + lane] = o1;   // query l+1
    }
}

extern "C" void kernel_launch(void* const* d_in, const int* in_sizes, int n_in,
                              void* d_out, int out_size, void* d_ws, size_t ws_size,
                              hipStream_t stream)
{
    const float* x = (const float*)d_in[0];
    float* out = (float*)d_out;
    dim3 grid(B_ * H_ * (L_ / TQ));
    dim3 block(512);
    natten1d_kernel<<<grid, block, 0, stream>>>(x, out);
}

// Round 2
// 13.451 us; speedup vs baseline: 2.7695x; 2.7695x over previous
//
#include <hip/hip_runtime.h>

#define B_ 2
#define L_ 2048
#define H_ 8
#define HD 64
#define K_ 63
#define TQ 64
#define NT (L_ / TQ)          // 32 query tiles per (b,h)
#define ROWS 128              // padded window union (126 used)
#define EXPC 0.1803368801111204f   // scale(=hd^-0.5=0.125) * log2(e)

typedef __attribute__((ext_vector_type(8))) short bf16x8;   // MFMA A/B operand
typedef __attribute__((ext_vector_type(4))) float f32x4;    // MFMA C/D operand
typedef __attribute__((ext_vector_type(4))) unsigned short u16x4;

// float -> bf16 bits, round-nearest-even
__device__ inline unsigned short f2bf(float f) {
    unsigned u = __float_as_uint(f);
    unsigned r = ((u >> 16) & 1u) + 0x7FFFu;
    return (unsigned short)((u + r) >> 16);
}

// Layouts (all ushort-indexed, XOR-swizzled at 16B-group granularity):
//  kv_sh [128 keys][64 d]   row=128B=8 groups;  grp ^= (row & 7)   (QK^T A/B frags: K-dim=d contiguous)
//  kvT_sh[64 d][128 keys]   row=256B=16 groups; grp ^= (d & 15)    (PV B frags: K-dim=keys contiguous)
//  pt_sh [wave][16 q][128 k] row=256B=16 groups; grp ^= (q & 15)   (PV A frags)
//
// MFMA 16x16x32 bf16 lane maps (m89/m91-verified convention):
//  A: row m = lane&15, k = (lane>>4)*8 + j   (8 contiguous k per lane -> one b128)
//  B: col n = lane&15, k = (lane>>4)*8 + j
//  D: col n = lane&15, row m = (lane>>4)*4 + reg
__global__ __launch_bounds__(256) void natten1d_mfma(
    const float* __restrict__ x, float* __restrict__ out)
{
    __shared__ unsigned short kv_sh [ROWS * 64];
    __shared__ unsigned short kvT_sh[64 * ROWS];
    __shared__ unsigned short pt_sh [4 * 16 * ROWS];

    const int bid = blockIdx.x;
    const int bh  = bid / NT;
    const int t   = bid % NT;
    const int b   = bh / H_;
    const int h   = bh % H_;
    const int l0  = t * TQ;
    const int key_base = min(max(l0 - K_ / 2, 0), L_ - K_);
    const int qoff     = l0 - key_base;          // 0 (tile 0) or 31

    const int tid = threadIdx.x;

    // ---------------- stage: global fp32 -> bf16 kv + kvT ----------------
    const float4* xb = (const float4*)x + (size_t)b * (L_ * H_ * HD / 4) + h * (HD / 4);
    #pragma unroll
    for (int it = 0; it < 8; ++it) {
        const int id = tid + it * 256;           // 2048 = 128 rows * 16 float4
        const int r  = id >> 4;
        const int d4 = id & 15;
        const int g  = key_base + r;
        float4 v = make_float4(0.f, 0.f, 0.f, 0.f);
        if (g < L_) v = xb[(size_t)g * (H_ * HD / 4) + d4];
        const unsigned short e0 = f2bf(v.x), e1 = f2bf(v.y),
                             e2 = f2bf(v.z), e3 = f2bf(v.w);
        // kv: byte = r*128 + ((d4>>1)^(r&7))*16 + (d4&1)*8
        const int ki = r * 64 + ((((d4 >> 1) ^ (r & 7))) << 3) + (d4 & 1) * 4;
        *(u16x4*)&kv_sh[ki] = (u16x4){e0, e1, e2, e3};
        // kvT: elem (d, r): idx = d*128 + ((r>>3)^(d&15))*8 + (r&7)
        const int d0 = d4 * 4;
        const unsigned short ev[4] = {e0, e1, e2, e3};
        #pragma unroll
        for (int e = 0; e < 4; ++e) {
            const int d = d0 + e;
            kvT_sh[d * 128 + (((r >> 3) ^ (d & 15)) << 3) + (r & 7)] = ev[e];
        }
    }
    __syncthreads();

    const int wave = tid >> 6;
    const int lane = tid & 63;
    const int lq = lane & 15;          // col-side lane index
    const int lg = lane >> 4;          // k-group

    // ---------------- S = Q * K^T (64 queries/block, 16/wave; 128 key cols) ----------------
    bf16x8 aq[2];
    {
        const int qrow = qoff + wave * 16 + lq;
        #pragma unroll
        for (int kc = 0; kc < 2; ++kc)
            aq[kc] = *(const bf16x8*)&kv_sh[qrow * 64 + (((kc * 4 + lg) ^ (qrow & 7)) << 3)];
    }
    f32x4 acc[8];
    #pragma unroll
    for (int nb = 0; nb < 8; ++nb) acc[nb] = (f32x4){0.f, 0.f, 0.f, 0.f};
    #pragma unroll
    for (int nb = 0; nb < 8; ++nb) {
        const int krow = nb * 16 + lq;
        const bf16x8 b0 = *(const bf16x8*)&kv_sh[krow * 64 + (((0 + lg) ^ (krow & 7)) << 3)];
        const bf16x8 b1 = *(const bf16x8*)&kv_sh[krow * 64 + (((4 + lg) ^ (krow & 7)) << 3)];
        acc[nb] = __builtin_amdgcn_mfma_f32_16x16x32_bf16(aq[0], b0, acc[nb], 0, 0, 0);
        acc[nb] = __builtin_amdgcn_mfma_f32_16x16x32_bf16(aq[1], b1, acc[nb], 0, 0, 0);
    }

    // ---------------- band mask + softmax (rows = 4 query regs) ----------------
    float rz[4];
    #pragma unroll
    for (int r = 0; r < 4; ++r) {
        const int q  = wave * 16 + lg * 4 + r;               // local query
        const int soff = min(max(l0 + q - K_ / 2, 0), L_ - K_) - key_base;
        float mrow = -1e30f;
        #pragma unroll
        for (int nb = 0; nb < 8; ++nb) {
            const int col = nb * 16 + lq;
            float s = acc[nb][r];
            s = ((unsigned)(col - soff) <= (unsigned)(K_ - 1)) ? s : -1e30f;
            acc[nb][r] = s;
            mrow = fmaxf(mrow, s);
        }
        #pragma unroll
        for (int o = 1; o <= 8; o <<= 1) mrow = fmaxf(mrow, __shfl_xor(mrow, o));
        float z = 0.f;
        #pragma unroll
        for (int nb = 0; nb < 8; ++nb) {
            const float e = exp2f((acc[nb][r] - mrow) * EXPC);
            acc[nb][r] = e;                                   // unnormalized P
            z += e;
        }
        #pragma unroll
        for (int o = 1; o <= 8; o <<= 1) z += __shfl_xor(z, o);
        rz[r] = 1.0f / z;                                     // folded into epilogue
    }

    // ---------------- P -> per-wave LDS tile (bf16, swizzled) ----------------
    unsigned short* ptw = &pt_sh[wave * 16 * 128];
    #pragma unroll
    for (int nb = 0; nb < 8; ++nb) {
        #pragma unroll
        for (int r = 0; r < 4; ++r) {
            const int q = lg * 4 + r;                         // row in pt tile
            const int k = nb * 16 + lq;                       // key col
            ptw[q * 128 + ((((nb * 2) + (lq >> 3)) ^ (q & 15)) << 3) + (lq & 7)]
                = f2bf(acc[nb][r]);
        }
    }

    // ---------------- O = P * KV ----------------
    bf16x8 ap[4];
    #pragma unroll
    for (int kc = 0; kc < 4; ++kc)
        ap[kc] = *(const bf16x8*)&ptw[lq * 128 + (((kc * 4 + lg) ^ (lq & 15)) << 3)];
    f32x4 o4[4];
    #pragma unroll
    for (int nb = 0; nb < 4; ++nb) o4[nb] = (f32x4){0.f, 0.f, 0.f, 0.f};
    #pragma unroll
    for (int nb = 0; nb < 4; ++nb) {
        const int d = nb * 16 + lq;
        #pragma unroll
        for (int kc = 0; kc < 4; ++kc) {
            const bf16x8 bv = *(const bf16x8*)&kvT_sh[d * 128 + (((kc * 4 + lg) ^ (d & 15)) << 3)];
            o4[nb] = __builtin_amdgcn_mfma_f32_16x16x32_bf16(ap[kc], bv, o4[nb], 0, 0, 0);
        }
    }

    // ---------------- epilogue: normalize + store fp32 ----------------
    #pragma unroll
    for (int nb = 0; nb < 4; ++nb) {
        const int d = nb * 16 + lq;
        #pragma unroll
        for (int r = 0; r < 4; ++r) {
            const int q = wave * 16 + lg * 4 + r;
            out[((size_t)(b * L_ + l0 + q) * H_ + h) * HD + d] = o4[nb][r] * rz[r];
        }
    }
}

extern "C" void kernel_launch(void* const* d_in, const int* in_sizes, int n_in,
                              void* d_out, int out_size, void* d_ws, size_t ws_size,
                              hipStream_t stream)
{
    const float* x = (const float*)d_in[0];
    float* out = (float*)d_out;
    natten1d_mfma<<<dim3(B_ * H_ * NT), dim3(256), 0, stream>>>(x, out);
}